// Round 1
// baseline (891.980 us; speedup 1.0000x reference)
//
#include <hip/hip_runtime.h>

#define IN_F 32
#define OUT_F 32
#define EDGE_F 16
#define BN_EPS 1e-5f
#define SLOPE 0.01f

// ---------------- K1: h0[n,:] = x[n,:] @ root + bias  -> agg (= d_out) ----------------
__global__ __launch_bounds__(256) void node_root_kernel(
    const float* __restrict__ x, const float* __restrict__ root,
    const float* __restrict__ bias, float* __restrict__ agg, int N) {
  __shared__ float rl[IN_F * OUT_F];
  __shared__ float bl[OUT_F];
  for (int t = threadIdx.x; t < IN_F * OUT_F; t += blockDim.x) rl[t] = root[t];
  if (threadIdx.x < OUT_F) bl[threadIdx.x] = bias[threadIdx.x];
  __syncthreads();

  int n = blockIdx.x * blockDim.x + threadIdx.x;
  bool valid = (n < N);
  int nu = valid ? n : 0;

  float xr[IN_F];
  const float4* xp = (const float4*)(x + (size_t)nu * IN_F);
#pragma unroll
  for (int q = 0; q < IN_F / 4; ++q) {
    float4 v = xp[q];
    xr[q * 4 + 0] = v.x; xr[q * 4 + 1] = v.y; xr[q * 4 + 2] = v.z; xr[q * 4 + 3] = v.w;
  }

  float acc[OUT_F];
#pragma unroll
  for (int o = 0; o < OUT_F; ++o) acc[o] = bl[o];
#pragma unroll
  for (int i = 0; i < IN_F; ++i) {
    float xi = xr[i];
#pragma unroll
    for (int o = 0; o < OUT_F; ++o) acc[o] = fmaf(xi, rl[i * OUT_F + o], acc[o]);
  }

  if (valid) {
    float4* op = (float4*)(agg + (size_t)n * OUT_F);
#pragma unroll
    for (int q = 0; q < OUT_F / 4; ++q)
      op[q] = make_float4(acc[q * 4 + 0], acc[q * 4 + 1], acc[q * 4 + 2], acc[q * 4 + 3]);
  }
}

// ---------------- K2: per-edge msg + scatter-add ----------------
// msg[e,o] = sum_i x[src,i] * ( sum_f ef[e,f]*W[f,i,o] + b[i,o] )
__global__ __launch_bounds__(256) void edge_kernel(
    const float* __restrict__ x, const float* __restrict__ ef,
    const float* __restrict__ W, const float* __restrict__ b,
    const int* __restrict__ ei, float* __restrict__ agg, int E) {
  __shared__ float Wl[EDGE_F * IN_F * OUT_F];  // 16384 floats = 64 KB

  int e = blockIdx.x * blockDim.x + threadIdx.x;
  bool valid = (e < E);
  int eu = valid ? e : 0;
  int s = ei[eu];       // src
  int d = ei[E + eu];   // dst

  float efr[EDGE_F];
  {
    const float4* ep = (const float4*)(ef + (size_t)eu * EDGE_F);
#pragma unroll
    for (int q = 0; q < EDGE_F / 4; ++q) {
      float4 v = ep[q];
      efr[q * 4 + 0] = v.x; efr[q * 4 + 1] = v.y; efr[q * 4 + 2] = v.z; efr[q * 4 + 3] = v.w;
    }
  }

  const float* xrow = x + (size_t)s * IN_F;

  float acc[OUT_F];
#pragma unroll
  for (int o = 0; o < OUT_F; ++o) acc[o] = 0.f;

  // ---- phase 1: bias part, b staged in (reused) LDS ----
  for (int t = threadIdx.x; t < IN_F * OUT_F; t += 256) Wl[t] = b[t];
  __syncthreads();
  for (int i = 0; i < IN_F; ++i) {  // runtime loop; LDS addr = i*128B + const imm
    float xi = xrow[i];
    const float* br = &Wl[i * OUT_F];
#pragma unroll
    for (int o = 0; o < OUT_F; ++o) acc[o] = fmaf(xi, br[o], acc[o]);
  }
  __syncthreads();

  // ---- phase 2: stage full W, heavy loop ----
  for (int t = threadIdx.x; t < EDGE_F * IN_F * OUT_F / 4; t += 256)
    ((float4*)Wl)[t] = ((const float4*)W)[t];
  __syncthreads();

  for (int i = 0; i < IN_F; ++i) {  // runtime loop (keeps code ~6KB)
    float xi = xrow[i];
#pragma unroll
    for (int f = 0; f < EDGE_F; ++f) {   // static: efr[] stays in registers
      float m = efr[f] * xi;
      const float* wr = &Wl[(f * IN_F + i) * OUT_F];
#pragma unroll
      for (int o = 0; o < OUT_F; ++o) acc[o] = fmaf(m, wr[o], acc[o]);
    }
  }

  if (valid) {
    float* dp = agg + (size_t)d * OUT_F;
#pragma unroll
    for (int o = 0; o < OUT_F; ++o) atomicAdd(dp + o, acc[o]);
  }
}

// ---------------- K3: BN stats (sum, sumsq per column) ----------------
__global__ __launch_bounds__(256) void bn_stats_kernel(
    const float* __restrict__ h, float* __restrict__ stats, int total) {
  int t = blockIdx.x * blockDim.x + threadIdx.x;
  int stride = gridDim.x * blockDim.x;  // multiple of 32 -> column fixed per thread
  float s = 0.f, s2 = 0.f;
  for (int idx = t; idx < total; idx += stride) {
    float v = h[idx];
    s += v;
    s2 = fmaf(v, v, s2);
  }
  __shared__ float ls[256], ls2[256];
  ls[threadIdx.x] = s;
  ls2[threadIdx.x] = s2;
  __syncthreads();
  if (threadIdx.x < 32) {
    float a = ls[threadIdx.x], a2 = ls2[threadIdx.x];
    for (int j = 32 + threadIdx.x; j < 256; j += 32) { a += ls[j]; a2 += ls2[j]; }
    atomicAdd(&stats[threadIdx.x], a);
    atomicAdd(&stats[32 + threadIdx.x], a2);
  }
}

// ---------------- K4: normalize + affine + LeakyReLU (in place) ----------------
__global__ __launch_bounds__(256) void bn_apply_kernel(
    float* __restrict__ h, const float* __restrict__ stats,
    const float* __restrict__ gamma, const float* __restrict__ beta,
    int total, float invN) {
  int t = blockIdx.x * blockDim.x + threadIdx.x;
  int i4 = t * 4;
  if (i4 >= total) return;
  float4 v = *(const float4*)(h + i4);
  float r[4] = {v.x, v.y, v.z, v.w};
  int o0 = i4 & 31;
#pragma unroll
  for (int j = 0; j < 4; ++j) {
    int o = o0 + j;
    float m = stats[o] * invN;
    float var = fmaf(-m, m, stats[32 + o] * invN);
    float sc = rsqrtf(var + BN_EPS) * gamma[o];
    float val = (r[j] - m) * sc + beta[o];
    r[j] = val >= 0.f ? val : SLOPE * val;
  }
  *(float4*)(h + i4) = make_float4(r[0], r[1], r[2], r[3]);
}

extern "C" void kernel_launch(void* const* d_in, const int* in_sizes, int n_in,
                              void* d_out, int out_size, void* d_ws, size_t ws_size,
                              hipStream_t stream) {
  const float* x     = (const float*)d_in[0];  // [N,32]
  const float* ef    = (const float*)d_in[1];  // [E,16]
  const float* W     = (const float*)d_in[2];  // [16,1024]
  const float* b     = (const float*)d_in[3];  // [1024]
  const float* root  = (const float*)d_in[4];  // [32,32]
  const float* bias  = (const float*)d_in[5];  // [32]
  const float* gamma = (const float*)d_in[6];  // [32]
  const float* beta  = (const float*)d_in[7];  // [32]
  const int*   ei    = (const int*)d_in[8];    // [2,E]

  float* out = (float*)d_out;     // doubles as the aggregation buffer h
  float* stats = (float*)d_ws;    // 64 floats: sum[32], sumsq[32]

  int N = in_sizes[0] / IN_F;
  int E = in_sizes[1] / EDGE_F;
  int total = N * OUT_F;

  hipMemsetAsync(stats, 0, 64 * sizeof(float), stream);

  node_root_kernel<<<(N + 255) / 256, 256, 0, stream>>>(x, root, bias, out, N);
  edge_kernel<<<(E + 255) / 256, 256, 0, stream>>>(x, ef, W, b, ei, out, E);
  bn_stats_kernel<<<1024, 256, 0, stream>>>(out, stats, total);
  bn_apply_kernel<<<(total / 4 + 255) / 256, 256, 0, stream>>>(out, stats, gamma, beta, total, 1.0f / (float)N);
}

// Round 2
// 335.622 us; speedup vs baseline: 2.6577x; 2.6577x over previous
//
#include <hip/hip_runtime.h>

#define IN_F 32
#define OUT_F 32
#define EDGE_F 16
#define BN_EPS 1e-5f
#define SLOPE 0.01f

// ---------------- K1: h0[n,:] = x[n,:] @ root + bias  -> agg (= d_out) ----------------
__global__ __launch_bounds__(256) void node_root_kernel(
    const float* __restrict__ x, const float* __restrict__ root,
    const float* __restrict__ bias, float* __restrict__ agg, int N) {
  __shared__ float rl[IN_F * OUT_F];
  __shared__ float bl[OUT_F];
  for (int t = threadIdx.x; t < IN_F * OUT_F; t += blockDim.x) rl[t] = root[t];
  if (threadIdx.x < OUT_F) bl[threadIdx.x] = bias[threadIdx.x];
  __syncthreads();

  int n = blockIdx.x * blockDim.x + threadIdx.x;
  bool valid = (n < N);
  int nu = valid ? n : 0;

  float xr[IN_F];
  const float4* xp = (const float4*)(x + (size_t)nu * IN_F);
#pragma unroll
  for (int q = 0; q < IN_F / 4; ++q) {
    float4 v = xp[q];
    xr[q * 4 + 0] = v.x; xr[q * 4 + 1] = v.y; xr[q * 4 + 2] = v.z; xr[q * 4 + 3] = v.w;
  }

  float acc[OUT_F];
#pragma unroll
  for (int o = 0; o < OUT_F; ++o) acc[o] = bl[o];
#pragma unroll
  for (int i = 0; i < IN_F; ++i) {
    float xi = xr[i];
#pragma unroll
    for (int o = 0; o < OUT_F; ++o) acc[o] = fmaf(xi, rl[i * OUT_F + o], acc[o]);
  }

  if (valid) {
    float4* op = (float4*)(agg + (size_t)n * OUT_F);
#pragma unroll
    for (int q = 0; q < OUT_F / 4; ++q)
      op[q] = make_float4(acc[q * 4 + 0], acc[q * 4 + 1], acc[q * 4 + 2], acc[q * 4 + 3]);
  }
}

// ---------------- K0: Y[n, f, o] = sum_i x[n,i] * W[f,i,o]   (f=16 slice uses b) ----------------
// Y layout: [N][17][32] row-contiguous (2176 B per node). Channel 16 = x @ b ("xb").
__global__ __launch_bounds__(256) void gemm_y_kernel(
    const float* __restrict__ x, const float* __restrict__ W,
    const float* __restrict__ b, float* __restrict__ Y, int N) {
  __shared__ float xl[32][33];          // +1 pad: conflict-free column reads
  __shared__ float Wl[4 * 32 * 32];     // 16 KB: 4 f-slices of [32i][32o]

  int f0 = blockIdx.y * 4;
  int n0 = blockIdx.x * 32;
  int tid = threadIdx.x;

  // stage x tile [32 nodes][32 feats]
  {
    int r = tid >> 3, p = tid & 7;
    int n = n0 + r;
    float4 v = make_float4(0.f, 0.f, 0.f, 0.f);
    if (n < N) v = *(const float4*)(x + (size_t)n * IN_F + p * 4);
    xl[r][p * 4 + 0] = v.x; xl[r][p * 4 + 1] = v.y;
    xl[r][p * 4 + 2] = v.z; xl[r][p * 4 + 3] = v.w;
  }
  // stage W tile: 4 f-slices (slice f==16 is b reshaped [32][32]; f>16 zero)
  {
    float4* Wl4 = (float4*)Wl;
#pragma unroll
    for (int k = 0; k < 4; ++k) {
      int idx = k * 256 + tid;     // float4 index within 4096-float tile
      int fi = idx >> 8;
      int rest = idx & 255;        // float4 within one 1024-float slice
      int f = f0 + fi;
      float4 v = make_float4(0.f, 0.f, 0.f, 0.f);
      if (f < 16)       v = *(const float4*)(W + (size_t)f * 1024 + rest * 4);
      else if (f == 16) v = *(const float4*)(b + rest * 4);
      Wl4[idx] = v;
    }
  }
  __syncthreads();

  int nl = tid >> 3, oq = tid & 7;
  int n = n0 + nl;
  const float4* Wl4 = (const float4*)Wl;
#pragma unroll
  for (int fi = 0; fi < 4; ++fi) {
    int f = f0 + fi;
    float4 acc = make_float4(0.f, 0.f, 0.f, 0.f);
#pragma unroll
    for (int i = 0; i < IN_F; ++i) {
      float xi = xl[nl][i];
      float4 w = Wl4[(fi * 32 + i) * 8 + oq];
      acc.x = fmaf(xi, w.x, acc.x);
      acc.y = fmaf(xi, w.y, acc.y);
      acc.z = fmaf(xi, w.z, acc.z);
      acc.w = fmaf(xi, w.w, acc.w);
    }
    if (n < N && f < 17)
      *(float4*)(Y + (size_t)n * 544 + f * 32 + oq * 4) = acc;
  }
}

// ---------------- K2new: light edge kernel: 8 threads/edge ----------------
// msg[e, o0..o0+3] = Y[s,16,o0..] + sum_f ef[e,f] * Y[s,f,o0..] ; atomicAdd into agg[d].
__global__ __launch_bounds__(256) void edge_light_kernel(
    const float* __restrict__ Y, const float* __restrict__ ef,
    const int* __restrict__ ei, float* __restrict__ agg, int E) {
  int g = blockIdx.x * 256 + threadIdx.x;
  if (g >= E * 8) return;
  int e = g >> 3, oq = g & 7;
  int s = ei[e];
  int d = ei[E + e];

  float efr[EDGE_F];
  const float4* ep = (const float4*)(ef + (size_t)e * EDGE_F);
#pragma unroll
  for (int q = 0; q < EDGE_F / 4; ++q) {
    float4 v = ep[q];
    efr[q * 4 + 0] = v.x; efr[q * 4 + 1] = v.y;
    efr[q * 4 + 2] = v.z; efr[q * 4 + 3] = v.w;
  }

  const float* yrow = Y + (size_t)s * 544 + oq * 4;
  float4 acc = *(const float4*)(yrow + 16 * 32);   // xb channel
#pragma unroll
  for (int f = 0; f < EDGE_F; ++f) {
    float4 w = *(const float4*)(yrow + f * 32);
    acc.x = fmaf(efr[f], w.x, acc.x);
    acc.y = fmaf(efr[f], w.y, acc.y);
    acc.z = fmaf(efr[f], w.z, acc.z);
    acc.w = fmaf(efr[f], w.w, acc.w);
  }

  float* dp = agg + (size_t)d * OUT_F + oq * 4;
  atomicAdd(dp + 0, acc.x);
  atomicAdd(dp + 1, acc.y);
  atomicAdd(dp + 2, acc.z);
  atomicAdd(dp + 3, acc.w);
}

// ---------------- Fallback (round-1) edge kernel: W staged in LDS ----------------
__global__ __launch_bounds__(256) void edge_kernel(
    const float* __restrict__ x, const float* __restrict__ ef,
    const float* __restrict__ W, const float* __restrict__ b,
    const int* __restrict__ ei, float* __restrict__ agg, int E) {
  __shared__ float Wl[EDGE_F * IN_F * OUT_F];

  int e = blockIdx.x * blockDim.x + threadIdx.x;
  bool valid = (e < E);
  int eu = valid ? e : 0;
  int s = ei[eu];
  int d = ei[E + eu];

  float efr[EDGE_F];
  {
    const float4* ep = (const float4*)(ef + (size_t)eu * EDGE_F);
#pragma unroll
    for (int q = 0; q < EDGE_F / 4; ++q) {
      float4 v = ep[q];
      efr[q * 4 + 0] = v.x; efr[q * 4 + 1] = v.y;
      efr[q * 4 + 2] = v.z; efr[q * 4 + 3] = v.w;
    }
  }

  const float* xrow = x + (size_t)s * IN_F;
  float acc[OUT_F];
#pragma unroll
  for (int o = 0; o < OUT_F; ++o) acc[o] = 0.f;

  for (int t = threadIdx.x; t < IN_F * OUT_F; t += 256) Wl[t] = b[t];
  __syncthreads();
  for (int i = 0; i < IN_F; ++i) {
    float xi = xrow[i];
    const float* br = &Wl[i * OUT_F];
#pragma unroll
    for (int o = 0; o < OUT_F; ++o) acc[o] = fmaf(xi, br[o], acc[o]);
  }
  __syncthreads();

  for (int t = threadIdx.x; t < EDGE_F * IN_F * OUT_F / 4; t += 256)
    ((float4*)Wl)[t] = ((const float4*)W)[t];
  __syncthreads();

  for (int i = 0; i < IN_F; ++i) {
    float xi = xrow[i];
#pragma unroll
    for (int f = 0; f < EDGE_F; ++f) {
      float m = efr[f] * xi;
      const float* wr = &Wl[(f * IN_F + i) * OUT_F];
#pragma unroll
      for (int o = 0; o < OUT_F; ++o) acc[o] = fmaf(m, wr[o], acc[o]);
    }
  }

  if (valid) {
    float* dp = agg + (size_t)d * OUT_F;
#pragma unroll
    for (int o = 0; o < OUT_F; ++o) atomicAdd(dp + o, acc[o]);
  }
}

// ---------------- K3: BN stats (sum, sumsq per column) ----------------
__global__ __launch_bounds__(256) void bn_stats_kernel(
    const float* __restrict__ h, float* __restrict__ stats, int total) {
  int t = blockIdx.x * blockDim.x + threadIdx.x;
  int stride = gridDim.x * blockDim.x;
  float s = 0.f, s2 = 0.f;
  for (int idx = t; idx < total; idx += stride) {
    float v = h[idx];
    s += v;
    s2 = fmaf(v, v, s2);
  }
  __shared__ float ls[256], ls2[256];
  ls[threadIdx.x] = s;
  ls2[threadIdx.x] = s2;
  __syncthreads();
  if (threadIdx.x < 32) {
    float a = ls[threadIdx.x], a2 = ls2[threadIdx.x];
    for (int j = 32 + threadIdx.x; j < 256; j += 32) { a += ls[j]; a2 += ls2[j]; }
    atomicAdd(&stats[threadIdx.x], a);
    atomicAdd(&stats[32 + threadIdx.x], a2);
  }
}

// ---------------- K4: normalize + affine + LeakyReLU (in place) ----------------
__global__ __launch_bounds__(256) void bn_apply_kernel(
    float* __restrict__ h, const float* __restrict__ stats,
    const float* __restrict__ gamma, const float* __restrict__ beta,
    int total, float invN) {
  int t = blockIdx.x * blockDim.x + threadIdx.x;
  int i4 = t * 4;
  if (i4 >= total) return;
  float4 v = *(const float4*)(h + i4);
  float r[4] = {v.x, v.y, v.z, v.w};
  int o0 = i4 & 31;
#pragma unroll
  for (int j = 0; j < 4; ++j) {
    int o = o0 + j;
    float m = stats[o] * invN;
    float var = fmaf(-m, m, stats[32 + o] * invN);
    float sc = rsqrtf(var + BN_EPS) * gamma[o];
    float val = (r[j] - m) * sc + beta[o];
    r[j] = val >= 0.f ? val : SLOPE * val;
  }
  *(float4*)(h + i4) = make_float4(r[0], r[1], r[2], r[3]);
}

extern "C" void kernel_launch(void* const* d_in, const int* in_sizes, int n_in,
                              void* d_out, int out_size, void* d_ws, size_t ws_size,
                              hipStream_t stream) {
  const float* x     = (const float*)d_in[0];
  const float* ef    = (const float*)d_in[1];
  const float* W     = (const float*)d_in[2];
  const float* b     = (const float*)d_in[3];
  const float* root  = (const float*)d_in[4];
  const float* bias  = (const float*)d_in[5];
  const float* gamma = (const float*)d_in[6];
  const float* beta  = (const float*)d_in[7];
  const int*   ei    = (const int*)d_in[8];

  float* out = (float*)d_out;
  float* stats = (float*)d_ws;                       // 64 floats
  float* Y = (float*)((char*)d_ws + 1024);           // [N][17][32]

  int N = in_sizes[0] / IN_F;
  int E = in_sizes[1] / EDGE_F;
  int total = N * OUT_F;
  size_t need = 1024 + (size_t)N * 544 * sizeof(float);

  hipMemsetAsync(stats, 0, 64 * sizeof(float), stream);

  if (ws_size >= need) {
    gemm_y_kernel<<<dim3((N + 31) / 32, 5), 256, 0, stream>>>(x, W, b, Y, N);
    node_root_kernel<<<(N + 255) / 256, 256, 0, stream>>>(x, root, bias, out, N);
    edge_light_kernel<<<(E * 8 + 255) / 256, 256, 0, stream>>>(Y, ef, ei, out, E);
  } else {
    node_root_kernel<<<(N + 255) / 256, 256, 0, stream>>>(x, root, bias, out, N);
    edge_kernel<<<(E + 255) / 256, 256, 0, stream>>>(x, ef, W, b, ei, out, E);
  }
  bn_stats_kernel<<<1024, 256, 0, stream>>>(out, stats, total);
  bn_apply_kernel<<<(total / 4 + 255) / 256, 256, 0, stream>>>(out, stats, gamma, beta, total, 1.0f / (float)N);
}